// Round 4
// baseline (201.348 us; speedup 1.0000x reference)
//
#include <hip/hip_runtime.h>
#include <hip/hip_bf16.h>
#include <math.h>
#include <limits.h>

typedef __attribute__((ext_vector_type(8))) short short8v;
typedef __attribute__((ext_vector_type(4))) float f32x4;

union U4 { uint4 u; short8v s; };

__device__ __forceinline__ uint32_t bf_hi_bits(float x) {
    uint32_t u = __float_as_uint(x);
    return (u + 0x7FFFu + ((u >> 16) & 1u)) >> 16;
}

// hw-convert split: returns (bf16_hi << 16) | bf16_lo
__device__ __forceinline__ uint32_t pack_split(float x) {
    __hip_bfloat16 h = __float2bfloat16(x);
    float fh = __bfloat162float(h);
    __hip_bfloat16 l = __float2bfloat16(x - fh);
    return ((uint32_t)__builtin_bit_cast(unsigned short, h) << 16)
         | (uint32_t)__builtin_bit_cast(unsigned short, l);
}

__device__ __forceinline__ float fast_tanh(float x) {
    float ax = fabsf(x);
    float e = __expf(2.0f * ax);
    float r = __builtin_amdgcn_rcpf(e + 1.0f);
    float t = fmaf(-2.0f, r, 1.0f);
    return copysignf(t, x);
}

__device__ __forceinline__ float Ffunc_f(float x, float y) {
    float e1 = __expf(-x * x - (y + 1.f) * (y + 1.f));
    float e2 = __expf(-x * x - y * y);
    float e3 = __expf(-(x + 1.f) * (x + 1.f) - y * y);
    float x3 = x * x * x;
    float y5 = y * y * y * y * y;
    return 3.f * (1.f - x) * (1.f - x) * e1
         - 10.f * (x * 0.2f - x3 - y5) * e2
         - __expf(-1.0986122886681098f * e3);
}

// Pack W1 (128x128) and W2 (128x64) into MFMA B-fragment order, bf16 hi/lo planes.
__global__ void pack_weights(const float* __restrict__ W1, const float* __restrict__ W2,
                             uint4* __restrict__ w1h, uint4* __restrict__ w1l,
                             uint4* __restrict__ w2h, uint4* __restrict__ w2l)
{
    const int b = blockIdx.x;
    const int tid = threadIdx.x;
    const int s = tid >> 6, lane = tid & 63, g = lane >> 4, c = lane & 15;
    const float* W; uint4 *oh, *ol; int t, ldw;
    if (b < 8) { W = W1; oh = w1h; ol = w1l; t = b;     ldw = 128; }
    else       { W = W2; oh = w2h; ol = w2l; t = b - 8; ldw = 64;  }
    const int n = 16 * t + c;
    uint32_t hb[8], lb[8];
    #pragma unroll
    for (int j = 0; j < 8; ++j) {
        int k = 32 * s + 8 * g + j;
        float v = W[k * ldw + n];
        uint32_t h = bf_hi_bits(v);
        float fh = __uint_as_float(h << 16);
        uint32_t l = bf_hi_bits(v - fh);
        hb[j] = h; lb[j] = l;
    }
    uint4 H = make_uint4(hb[0] | (hb[1] << 16), hb[2] | (hb[3] << 16),
                         hb[4] | (hb[5] << 16), hb[6] | (hb[7] << 16));
    uint4 L = make_uint4(lb[0] | (lb[1] << 16), lb[2] | (lb[3] << 16),
                         lb[4] | (lb[5] << 16), lb[6] | (lb[7] << 16));
    oh[(t * 4 + s) * 64 + lane] = H;
    ol[(t * 4 + s) * 64 + lane] = L;
}

#define MFMA __builtin_amdgcn_mfma_f32_16x16x32_bf16

__global__ __launch_bounds__(256, 6)
void fused_mlp(const int* __restrict__ data, const float* __restrict__ embed,
               const float* __restrict__ b1, const float* __restrict__ b2,
               const float* __restrict__ W3, const float* __restrict__ b3,
               const uint4* __restrict__ w1h, const uint4* __restrict__ w1l,
               const uint4* __restrict__ w2h, const uint4* __restrict__ w2l,
               float* __restrict__ wsF, float2* __restrict__ wsO,
               int* __restrict__ wsI, int N)
{
    __shared__ uint32_t chunk[4][16 * 33];   // per-wave h1 strip: packed hi|lo, 32 cols
    __shared__ uint32_t embs_pk[48];
    __shared__ float b1s[128], W3s[128], b2s[64], b3s[2];
    __shared__ float candF[4];
    __shared__ int candI[4];
    __shared__ float2 candO[4];

    const int tid = threadIdx.x;
    if (tid < 48) {
        float e = embed[tid];
        uint32_t h = bf_hi_bits(e);
        float fh = __uint_as_float(h << 16);
        uint32_t l = bf_hi_bits(e - fh);
        embs_pk[tid] = (h << 16) | l;
    }
    if (tid < 128) { b1s[tid] = b1[tid]; W3s[tid] = W3[tid]; }
    else if (tid < 192) b2s[tid - 128] = b2[tid - 128];
    if (tid < 2) b3s[tid] = b3[tid];
    __syncthreads();

    const int w = tid >> 6, lane = tid & 63, g = lane >> 4, c = lane & 15;
    const int base = blockIdx.x << 6;

    // ---- x A-fragments (hi/lo) straight from data-gather, in registers ----
    const int rowA = base + 16 * w + c;
    const size_t drow = (size_t)min(rowA, N - 1) * 128;
    uint4 xh[4], xl[4];
    #pragma unroll
    for (int s = 0; s < 4; ++s) {
        const int4* dp = (const int4*)&data[drow + 32 * s + 8 * g];
        int4 d0 = dp[0], d1 = dp[1];
        uint32_t p0 = embs_pk[d0.x], p1 = embs_pk[d0.y], p2 = embs_pk[d0.z], p3 = embs_pk[d0.w];
        uint32_t p4 = embs_pk[d1.x], p5 = embs_pk[d1.y], p6 = embs_pk[d1.z], p7 = embs_pk[d1.w];
        xh[s] = make_uint4((p1 & 0xFFFF0000u) | (p0 >> 16), (p3 & 0xFFFF0000u) | (p2 >> 16),
                           (p5 & 0xFFFF0000u) | (p4 >> 16), (p7 & 0xFFFF0000u) | (p6 >> 16));
        xl[s] = make_uint4((p1 << 16) | (p0 & 0xFFFFu), (p3 << 16) | (p2 & 0xFFFFu),
                           (p5 << 16) | (p4 & 0xFFFFu), (p7 << 16) | (p6 & 0xFFFFu));
    }

    uint32_t* ck = chunk[w];
    f32x4 acc2[4];
    #pragma unroll
    for (int t2 = 0; t2 < 4; ++t2) {
        float bv = b2s[16 * t2 + c];
        acc2[t2] = (f32x4){bv, bv, bv, bv};
    }

    // ---- fused layer1 -> layer2, 32 h1-cols at a time ----
    #pragma unroll
    for (int s2 = 0; s2 < 4; ++s2) {
        // layer-1 tiles t0 = 2*s2, t1 = 2*s2+1
        float bv0 = b1s[32 * s2 + c], bv1 = b1s[32 * s2 + 16 + c];
        f32x4 a0 = (f32x4){bv0, bv0, bv0, bv0};
        f32x4 a1 = (f32x4){bv1, bv1, bv1, bv1};
        #pragma unroll
        for (int s = 0; s < 4; ++s) {
            U4 bh0, bl0, bh1, bl1, ah, al;
            bh0.u = w1h[(8 * s2 + s) * 64 + lane];
            bl0.u = w1l[(8 * s2 + s) * 64 + lane];
            bh1.u = w1h[(8 * s2 + 4 + s) * 64 + lane];
            bl1.u = w1l[(8 * s2 + 4 + s) * 64 + lane];
            ah.u = xh[s]; al.u = xl[s];
            a0 = MFMA(ah.s, bh0.s, a0, 0, 0, 0);
            a0 = MFMA(al.s, bh0.s, a0, 0, 0, 0);
            a0 = MFMA(ah.s, bl0.s, a0, 0, 0, 0);
            a1 = MFMA(ah.s, bh1.s, a1, 0, 0, 0);
            a1 = MFMA(al.s, bh1.s, a1, 0, 0, 0);
            a1 = MFMA(ah.s, bl1.s, a1, 0, 0, 0);
        }
        // relu + split + pack -> per-wave LDS chunk  (D layout: row=4g+r, col=16u+c)
        #pragma unroll
        for (int r = 0; r < 4; ++r) {
            ck[(4 * g + r) * 33 + c]      = pack_split(fmaxf(a0[r], 0.f));
            ck[(4 * g + r) * 33 + 16 + c] = pack_split(fmaxf(a1[r], 0.f));
        }
        // read back as layer-2 A-fragment (k-slice s2): lane needs row c, cols 8g+j
        uint32_t q0 = ck[c * 33 + 8 * g + 0], q1 = ck[c * 33 + 8 * g + 1];
        uint32_t q2 = ck[c * 33 + 8 * g + 2], q3 = ck[c * 33 + 8 * g + 3];
        uint32_t q4 = ck[c * 33 + 8 * g + 4], q5 = ck[c * 33 + 8 * g + 5];
        uint32_t q6 = ck[c * 33 + 8 * g + 6], q7 = ck[c * 33 + 8 * g + 7];
        U4 ah2, al2;
        ah2.u = make_uint4((q1 & 0xFFFF0000u) | (q0 >> 16), (q3 & 0xFFFF0000u) | (q2 >> 16),
                           (q5 & 0xFFFF0000u) | (q4 >> 16), (q7 & 0xFFFF0000u) | (q6 >> 16));
        al2.u = make_uint4((q1 << 16) | (q0 & 0xFFFFu), (q3 << 16) | (q2 & 0xFFFFu),
                           (q5 << 16) | (q4 & 0xFFFFu), (q7 << 16) | (q6 & 0xFFFFu));
        #pragma unroll
        for (int t2 = 0; t2 < 4; ++t2) {
            U4 b2h, b2l;
            b2h.u = w2h[(t2 * 4 + s2) * 64 + lane];
            b2l.u = w2l[(t2 * 4 + s2) * 64 + lane];
            acc2[t2] = MFMA(ah2.s, b2h.s, acc2[t2], 0, 0, 0);
            acc2[t2] = MFMA(al2.s, b2h.s, acc2[t2], 0, 0, 0);
            acc2[t2] = MFMA(ah2.s, b2l.s, acc2[t2], 0, 0, 0);
        }
    }

    // ---- tanh + layer-3 partials in-register ----
    float po0[4] = {0.f, 0.f, 0.f, 0.f};
    float po1[4] = {0.f, 0.f, 0.f, 0.f};
    #pragma unroll
    for (int t2 = 0; t2 < 4; ++t2) {
        int col = 16 * t2 + c;
        float w30 = W3s[2 * col], w31 = W3s[2 * col + 1];
        #pragma unroll
        for (int r = 0; r < 4; ++r) {
            float h = fast_tanh(acc2[t2][r]);
            po0[r] = fmaf(h, w30, po0[r]);
            po1[r] = fmaf(h, w31, po1[r]);
        }
    }
    // allreduce over c>>2 groups (xor 4, 8)
    #pragma unroll
    for (int r = 0; r < 4; ++r) {
        po0[r] += __shfl_xor(po0[r], 4, 64);
        po0[r] += __shfl_xor(po0[r], 8, 64);
        po1[r] += __shfl_xor(po1[r], 4, 64);
        po1[r] += __shfl_xor(po1[r], 8, 64);
    }
    // lane takes row rsel = c>>2 (static-index select), then sum over c&3
    const int rsel = c >> 2;
    float v0 = (rsel == 0) ? po0[0] : (rsel == 1) ? po0[1] : (rsel == 2) ? po0[2] : po0[3];
    float v1 = (rsel == 0) ? po1[0] : (rsel == 1) ? po1[1] : (rsel == 2) ? po1[2] : po1[3];
    v0 += __shfl_xor(v0, 1, 64); v0 += __shfl_xor(v0, 2, 64);
    v1 += __shfl_xor(v1, 1, 64); v1 += __shfl_xor(v1, 2, 64);

    const int row = base + 16 * w + 4 * g + rsel;
    float o0 = v0 + b3s[0], o1 = v1 + b3s[1];
    float Fv = -INFINITY; int idx = INT_MAX;
    if (row < N) { Fv = Ffunc_f(o0, o1); idx = row; }

    // 64-lane argmax reduce, first-index tie-break (duplicate rows share idx)
    #pragma unroll
    for (int m = 32; m > 0; m >>= 1) {
        float Fo = __shfl_xor(Fv, m, 64);
        int io   = __shfl_xor(idx, m, 64);
        float c0 = __shfl_xor(o0, m, 64);
        float c1 = __shfl_xor(o1, m, 64);
        if (Fo > Fv || (Fo == Fv && io < idx)) { Fv = Fo; idx = io; o0 = c0; o1 = c1; }
    }
    if (lane == 0) { candF[w] = Fv; candI[w] = idx; candO[w] = make_float2(o0, o1); }
    __syncthreads();
    if (tid == 0) {
        float bF = candF[0]; int bI = candI[0]; float2 bO = candO[0];
        #pragma unroll
        for (int u = 1; u < 4; ++u) {
            if (candF[u] > bF || (candF[u] == bF && candI[u] < bI)) {
                bF = candF[u]; bI = candI[u]; bO = candO[u];
            }
        }
        wsF[blockIdx.x] = bF; wsI[blockIdx.x] = bI; wsO[blockIdx.x] = bO;
    }
}

__global__ __launch_bounds__(256, 1)
void reduce_cands(const float* __restrict__ wsF, const float2* __restrict__ wsO,
                  const int* __restrict__ wsI, int nB, float* __restrict__ out)
{
    __shared__ float sF[256];
    __shared__ int sI[256];
    __shared__ float2 sO[256];
    const int tid = threadIdx.x;
    float Fv = -INFINITY; int idx = INT_MAX; float2 o = make_float2(0.f, 0.f);
    for (int u = tid; u < nB; u += 256) {
        float f = wsF[u]; int i = wsI[u];
        if (f > Fv || (f == Fv && i < idx)) { Fv = f; idx = i; o = wsO[u]; }
    }
    sF[tid] = Fv; sI[tid] = idx; sO[tid] = o;
    __syncthreads();
    if (tid == 0) {
        for (int u = 1; u < 256; ++u) {
            if (sF[u] > Fv || (sF[u] == Fv && sI[u] < idx)) { Fv = sF[u]; idx = sI[u]; o = sO[u]; }
        }
        out[0] = o.x;
        out[1] = o.y;
    }
}

extern "C" void kernel_launch(void* const* d_in, const int* in_sizes, int n_in,
                              void* d_out, int out_size, void* d_ws, size_t ws_size,
                              hipStream_t stream) {
    const int*   data  = (const int*)d_in[0];
    const float* embed = (const float*)d_in[1];
    const float* W1    = (const float*)d_in[2];
    const float* b1    = (const float*)d_in[3];
    const float* W2    = (const float*)d_in[4];
    const float* b2    = (const float*)d_in[5];
    const float* W3    = (const float*)d_in[6];
    const float* b3    = (const float*)d_in[7];

    const int N = in_sizes[0] / 128;
    const int nTiles = (N + 63) >> 6;

    char* ws = (char*)d_ws;
    uint4* w1h = (uint4*)ws;            // 32 KB (2048 uint4)
    uint4* w1l = w1h + 2048;            // 32 KB
    uint4* w2h = w1l + 2048;            // 16 KB (1024 uint4)
    uint4* w2l = w2h + 1024;            // 16 KB
    char* ws2 = ws + 98304;
    float2* wsO = (float2*)ws2;                          // 8B * nTiles (8-aligned)
    float*  wsF = (float*)(ws2 + (size_t)nTiles * 8);
    int*    wsI = (int*)(ws2 + (size_t)nTiles * 12);

    pack_weights<<<12, 256, 0, stream>>>(W1, W2, w1h, w1l, w2h, w2l);
    fused_mlp<<<nTiles, 256, 0, stream>>>(data, embed, b1, b2, W3, b3,
                                          w1h, w1l, w2h, w2l, wsF, wsO, wsI, N);
    reduce_cands<<<1, 256, 0, stream>>>(wsF, wsO, wsI, nTiles, (float*)d_out);
}

// Round 5
// 156.577 us; speedup vs baseline: 1.2859x; 1.2859x over previous
//
#include <hip/hip_runtime.h>
#include <hip/hip_bf16.h>
#include <math.h>
#include <limits.h>

typedef __attribute__((ext_vector_type(8))) short short8v;
typedef __attribute__((ext_vector_type(4))) float f32x4;

union U4 { uint4 u; short8v s; };

__device__ __forceinline__ uint32_t bf_hi_bits(float x) {
    uint32_t u = __float_as_uint(x);
    return (u + 0x7FFFu + ((u >> 16) & 1u)) >> 16;
}

// hw-convert split: returns (bf16_hi << 16) | bf16_lo
__device__ __forceinline__ uint32_t pack_split(float x) {
    __hip_bfloat16 h = __float2bfloat16(x);
    float fh = __bfloat162float(h);
    __hip_bfloat16 l = __float2bfloat16(x - fh);
    return ((uint32_t)__builtin_bit_cast(unsigned short, h) << 16)
         | (uint32_t)__builtin_bit_cast(unsigned short, l);
}

__device__ __forceinline__ float fast_tanh(float x) {
    float ax = fabsf(x);
    float e = __expf(2.0f * ax);
    float r = __builtin_amdgcn_rcpf(e + 1.0f);
    float t = fmaf(-2.0f, r, 1.0f);
    return copysignf(t, x);
}

__device__ __forceinline__ float Ffunc_f(float x, float y) {
    float e1 = __expf(-x * x - (y + 1.f) * (y + 1.f));
    float e2 = __expf(-x * x - y * y);
    float e3 = __expf(-(x + 1.f) * (x + 1.f) - y * y);
    float x3 = x * x * x;
    float y5 = y * y * y * y * y;
    return 3.f * (1.f - x) * (1.f - x) * e1
         - 10.f * (x * 0.2f - x3 - y5) * e2
         - __expf(-1.0986122886681098f * e3);
}

// Pack W1 (128x128) and W2 (128x64) into MFMA fragment order, bf16 hi/lo planes.
__global__ void pack_weights(const float* __restrict__ W1, const float* __restrict__ W2,
                             uint4* __restrict__ w1h, uint4* __restrict__ w1l,
                             uint4* __restrict__ w2h, uint4* __restrict__ w2l)
{
    const int b = blockIdx.x;
    const int tid = threadIdx.x;
    const int s = tid >> 6, lane = tid & 63, g = lane >> 4, c = lane & 15;
    const float* W; uint4 *oh, *ol; int t, ldw;
    if (b < 8) { W = W1; oh = w1h; ol = w1l; t = b;     ldw = 128; }
    else       { W = W2; oh = w2h; ol = w2l; t = b - 8; ldw = 64;  }
    const int n = 16 * t + c;
    uint32_t hb[8], lb[8];
    #pragma unroll
    for (int j = 0; j < 8; ++j) {
        int k = 32 * s + 8 * g + j;
        float v = W[k * ldw + n];
        uint32_t h = bf_hi_bits(v);
        float fh = __uint_as_float(h << 16);
        uint32_t l = bf_hi_bits(v - fh);
        hb[j] = h; lb[j] = l;
    }
    uint4 H = make_uint4(hb[0] | (hb[1] << 16), hb[2] | (hb[3] << 16),
                         hb[4] | (hb[5] << 16), hb[6] | (hb[7] << 16));
    uint4 L = make_uint4(lb[0] | (lb[1] << 16), lb[2] | (lb[3] << 16),
                         lb[4] | (lb[5] << 16), lb[6] | (lb[7] << 16));
    oh[(t * 4 + s) * 64 + lane] = H;
    ol[(t * 4 + s) * 64 + lane] = L;
}

#define MFMA __builtin_amdgcn_mfma_f32_16x16x32_bf16

__global__ __launch_bounds__(256, 4)
void fused_mlp(const int* __restrict__ data, const float* __restrict__ embed,
               const float* __restrict__ b1, const float* __restrict__ b2,
               const float* __restrict__ W3, const float* __restrict__ b3,
               const uint4* __restrict__ w1h, const uint4* __restrict__ w1l,
               const uint4* __restrict__ w2h, const uint4* __restrict__ w2l,
               float* __restrict__ wsF, float2* __restrict__ wsO,
               int* __restrict__ wsI, int N)
{
    __shared__ uint32_t embs_pk[48];
    __shared__ float b1s[128], W3s[128], b2s[64], b3s[2];
    __shared__ float candF[4];
    __shared__ int candI[4];
    __shared__ float2 candO[4];

    const int tid = threadIdx.x;
    if (tid < 48) {
        float e = embed[tid];
        uint32_t h = bf_hi_bits(e);
        float fh = __uint_as_float(h << 16);
        uint32_t l = bf_hi_bits(e - fh);
        embs_pk[tid] = (h << 16) | l;
    }
    if (tid < 128) { b1s[tid] = b1[tid]; W3s[tid] = W3[tid]; }
    else if (tid < 192) b2s[tid - 128] = b2[tid - 128];
    if (tid < 2) b3s[tid] = b3[tid];
    __syncthreads();

    const int w = tid >> 6, lane = tid & 63, g = lane >> 4, c = lane & 15;
    const int base = blockIdx.x << 6;

    // ---- x fragments (hi/lo) straight from data-gather, in registers ----
    const int rowA = base + 16 * w + c;
    const size_t drow = (size_t)min(rowA, N - 1) * 128;
    uint4 xh[4], xl[4];
    #pragma unroll
    for (int s = 0; s < 4; ++s) {
        const int4* dp = (const int4*)&data[drow + 32 * s + 8 * g];
        int4 d0 = dp[0], d1 = dp[1];
        uint32_t p0 = embs_pk[d0.x], p1 = embs_pk[d0.y], p2 = embs_pk[d0.z], p3 = embs_pk[d0.w];
        uint32_t p4 = embs_pk[d1.x], p5 = embs_pk[d1.y], p6 = embs_pk[d1.z], p7 = embs_pk[d1.w];
        xh[s] = make_uint4((p1 & 0xFFFF0000u) | (p0 >> 16), (p3 & 0xFFFF0000u) | (p2 >> 16),
                           (p5 & 0xFFFF0000u) | (p4 >> 16), (p7 & 0xFFFF0000u) | (p6 >> 16));
        xl[s] = make_uint4((p1 << 16) | (p0 & 0xFFFFu), (p3 << 16) | (p2 & 0xFFFFu),
                           (p5 << 16) | (p4 & 0xFFFFu), (p7 << 16) | (p6 & 0xFFFFu));
    }

    // bpermute source lanes for the h1 quad redistribution (constant per lane)
    const int src0 = ((g & 1) << 5) + c;   // lane 32*(g&1) + c
    const int src1 = src0 + 16;

    f32x4 acc2[4];
    #pragma unroll
    for (int t2 = 0; t2 < 4; ++t2) {
        float bv = b2s[16 * t2 + c];
        acc2[t2] = (f32x4){bv, bv, bv, bv};
    }

    // ---- fused layer1 (swapped operands -> h1^T in regs) -> shuffle -> layer2 ----
    #pragma unroll
    for (int s2 = 0; s2 < 4; ++s2) {
        // swapped MFMA: D = W1tile^T . x^T  -> lane (g,c) holds h1[xrow=c][col=16t+4g+r]
        f32x4 aA, aB;
        #pragma unroll
        for (int r = 0; r < 4; ++r) {
            aA[r] = b1s[32 * s2 + 4 * g + r];
            aB[r] = b1s[32 * s2 + 16 + 4 * g + r];
        }
        #pragma unroll
        for (int s = 0; s < 4; ++s) {
            U4 bh0, bl0, bh1, bl1, ah, al;
            bh0.u = w1h[(8 * s2 + s) * 64 + lane];
            bl0.u = w1l[(8 * s2 + s) * 64 + lane];
            bh1.u = w1h[(8 * s2 + 4 + s) * 64 + lane];
            bl1.u = w1l[(8 * s2 + 4 + s) * 64 + lane];
            ah.u = xh[s]; al.u = xl[s];
            aA = MFMA(bh0.s, ah.s, aA, 0, 0, 0);
            aA = MFMA(bh0.s, al.s, aA, 0, 0, 0);
            aA = MFMA(bl0.s, ah.s, aA, 0, 0, 0);
            aB = MFMA(bh1.s, ah.s, aB, 0, 0, 0);
            aB = MFMA(bh1.s, al.s, aB, 0, 0, 0);
            aB = MFMA(bl1.s, ah.s, aB, 0, 0, 0);
        }
        // relu + split + pack (u32 = hi|lo), still transposed
        uint32_t pA[4], pB[4];
        #pragma unroll
        for (int r = 0; r < 4; ++r) {
            pA[r] = pack_split(fmaxf(aA[r], 0.f));
            pB[r] = pack_split(fmaxf(aB[r], 0.f));
        }
        // quad redistribution across g at fixed c: dest (g,c) elem j
        //  <- lane (2*(g&1) + (j>=4))*16 + c, reg r=j&3, tile A if g<2 else B
        uint32_t q0[4], q1[4];
        #pragma unroll
        for (int r = 0; r < 4; ++r) {
            uint32_t a0v = __shfl(pA[r], src0, 64);
            uint32_t b0v = __shfl(pB[r], src0, 64);
            uint32_t a1v = __shfl(pA[r], src1, 64);
            uint32_t b1v = __shfl(pB[r], src1, 64);
            q0[r] = (lane < 32) ? a0v : b0v;
            q1[r] = (lane < 32) ? a1v : b1v;
        }
        U4 ah2, al2;
        ah2.u = make_uint4((q0[1] & 0xFFFF0000u) | (q0[0] >> 16),
                           (q0[3] & 0xFFFF0000u) | (q0[2] >> 16),
                           (q1[1] & 0xFFFF0000u) | (q1[0] >> 16),
                           (q1[3] & 0xFFFF0000u) | (q1[2] >> 16));
        al2.u = make_uint4((q0[1] << 16) | (q0[0] & 0xFFFFu),
                           (q0[3] << 16) | (q0[2] & 0xFFFFu),
                           (q1[1] << 16) | (q1[0] & 0xFFFFu),
                           (q1[3] << 16) | (q1[2] & 0xFFFFu));
        // layer-2 k-slice s2 (normal operand order)
        #pragma unroll
        for (int t2 = 0; t2 < 4; ++t2) {
            U4 b2h, b2l;
            b2h.u = w2h[(t2 * 4 + s2) * 64 + lane];
            b2l.u = w2l[(t2 * 4 + s2) * 64 + lane];
            acc2[t2] = MFMA(ah2.s, b2h.s, acc2[t2], 0, 0, 0);
            acc2[t2] = MFMA(al2.s, b2h.s, acc2[t2], 0, 0, 0);
            acc2[t2] = MFMA(ah2.s, b2l.s, acc2[t2], 0, 0, 0);
        }
    }

    // ---- tanh + layer-3 partials in-register ----
    float po0[4] = {0.f, 0.f, 0.f, 0.f};
    float po1[4] = {0.f, 0.f, 0.f, 0.f};
    #pragma unroll
    for (int t2 = 0; t2 < 4; ++t2) {
        int col = 16 * t2 + c;
        float w30 = W3s[2 * col], w31 = W3s[2 * col + 1];
        #pragma unroll
        for (int r = 0; r < 4; ++r) {
            float h = fast_tanh(acc2[t2][r]);
            po0[r] = fmaf(h, w30, po0[r]);
            po1[r] = fmaf(h, w31, po1[r]);
        }
    }
    #pragma unroll
    for (int r = 0; r < 4; ++r) {
        po0[r] += __shfl_xor(po0[r], 4, 64);
        po0[r] += __shfl_xor(po0[r], 8, 64);
        po1[r] += __shfl_xor(po1[r], 4, 64);
        po1[r] += __shfl_xor(po1[r], 8, 64);
    }
    const int rsel = c >> 2;
    float v0 = (rsel == 0) ? po0[0] : (rsel == 1) ? po0[1] : (rsel == 2) ? po0[2] : po0[3];
    float v1 = (rsel == 0) ? po1[0] : (rsel == 1) ? po1[1] : (rsel == 2) ? po1[2] : po1[3];
    v0 += __shfl_xor(v0, 1, 64); v0 += __shfl_xor(v0, 2, 64);
    v1 += __shfl_xor(v1, 1, 64); v1 += __shfl_xor(v1, 2, 64);

    const int row = base + 16 * w + 4 * g + rsel;
    float o0 = v0 + b3s[0], o1 = v1 + b3s[1];
    float Fv = -INFINITY; int idx = INT_MAX;
    if (row < N) { Fv = Ffunc_f(o0, o1); idx = row; }

    #pragma unroll
    for (int m = 32; m > 0; m >>= 1) {
        float Fo = __shfl_xor(Fv, m, 64);
        int io   = __shfl_xor(idx, m, 64);
        float c0 = __shfl_xor(o0, m, 64);
        float c1 = __shfl_xor(o1, m, 64);
        if (Fo > Fv || (Fo == Fv && io < idx)) { Fv = Fo; idx = io; o0 = c0; o1 = c1; }
    }
    if (lane == 0) { candF[w] = Fv; candI[w] = idx; candO[w] = make_float2(o0, o1); }
    __syncthreads();
    if (tid == 0) {
        float bF = candF[0]; int bI = candI[0]; float2 bO = candO[0];
        #pragma unroll
        for (int u = 1; u < 4; ++u) {
            if (candF[u] > bF || (candF[u] == bF && candI[u] < bI)) {
                bF = candF[u]; bI = candI[u]; bO = candO[u];
            }
        }
        wsF[blockIdx.x] = bF; wsI[blockIdx.x] = bI; wsO[blockIdx.x] = bO;
    }
}

__global__ __launch_bounds__(256, 1)
void reduce_cands(const float* __restrict__ wsF, const float2* __restrict__ wsO,
                  const int* __restrict__ wsI, int nB, float* __restrict__ out)
{
    __shared__ float sF[4];
    __shared__ int sI[4];
    __shared__ float2 sO[4];
    const int tid = threadIdx.x;
    const int w = tid >> 6, lane = tid & 63;
    float Fv = -INFINITY; int idx = INT_MAX; float2 o = make_float2(0.f, 0.f);
    for (int u = tid; u < nB; u += 256) {
        float f = wsF[u]; int i = wsI[u];
        if (f > Fv || (f == Fv && i < idx)) { Fv = f; idx = i; o = wsO[u]; }
    }
    #pragma unroll
    for (int m = 32; m > 0; m >>= 1) {
        float Fo = __shfl_xor(Fv, m, 64);
        int io   = __shfl_xor(idx, m, 64);
        float c0 = __shfl_xor(o.x, m, 64);
        float c1 = __shfl_xor(o.y, m, 64);
        if (Fo > Fv || (Fo == Fv && io < idx)) { Fv = Fo; idx = io; o = make_float2(c0, c1); }
    }
    if (lane == 0) { sF[w] = Fv; sI[w] = idx; sO[w] = o; }
    __syncthreads();
    if (tid == 0) {
        float bF = sF[0]; int bI = sI[0]; float2 bO = sO[0];
        #pragma unroll
        for (int u = 1; u < 4; ++u) {
            if (sF[u] > bF || (sF[u] == bF && sI[u] < bI)) { bF = sF[u]; bI = sI[u]; bO = sO[u]; }
        }
        out[0] = bO.x;
        out[1] = bO.y;
    }
}

extern "C" void kernel_launch(void* const* d_in, const int* in_sizes, int n_in,
                              void* d_out, int out_size, void* d_ws, size_t ws_size,
                              hipStream_t stream) {
    const int*   data  = (const int*)d_in[0];
    const float* embed = (const float*)d_in[1];
    const float* W1    = (const float*)d_in[2];
    const float* b1    = (const float*)d_in[3];
    const float* W2    = (const float*)d_in[4];
    const float* b2    = (const float*)d_in[5];
    const float* W3    = (const float*)d_in[6];
    const float* b3    = (const float*)d_in[7];

    const int N = in_sizes[0] / 128;
    const int nTiles = (N + 63) >> 6;

    char* ws = (char*)d_ws;
    uint4* w1h = (uint4*)ws;            // 32 KB (2048 uint4)
    uint4* w1l = w1h + 2048;            // 32 KB
    uint4* w2h = w1l + 2048;            // 16 KB (1024 uint4)
    uint4* w2l = w2h + 1024;            // 16 KB
    char* ws2 = ws + 98304;
    float2* wsO = (float2*)ws2;                          // 8B * nTiles (8-aligned)
    float*  wsF = (float*)(ws2 + (size_t)nTiles * 8);
    int*    wsI = (int*)(ws2 + (size_t)nTiles * 12);

    pack_weights<<<12, 256, 0, stream>>>(W1, W2, w1h, w1l, w2h, w2l);
    fused_mlp<<<nTiles, 256, 0, stream>>>(data, embed, b1, b2, W3, b3,
                                          w1h, w1l, w2h, w2l, wsF, wsO, wsI, N);
    reduce_cands<<<1, 256, 0, stream>>>(wsF, wsO, wsI, nTiles, (float*)d_out);
}

// Round 6
// 80.156 us; speedup vs baseline: 2.5119x; 1.9534x over previous
//
#include <hip/hip_runtime.h>
#include <hip/hip_bf16.h>
#include <math.h>
#include <limits.h>

typedef __attribute__((ext_vector_type(8))) short short8v;
typedef __attribute__((ext_vector_type(4))) float f32x4;

union U4 { uint4 u; short8v s; };

__device__ __forceinline__ uint32_t bf_hi_bits(float x) {
    uint32_t u = __float_as_uint(x);
    return (u + 0x7FFFu + ((u >> 16) & 1u)) >> 16;
}

// hw-convert split: returns (bf16_hi << 16) | bf16_lo
__device__ __forceinline__ uint32_t pack_split(float x) {
    __hip_bfloat16 h = __float2bfloat16(x);
    float fh = __bfloat162float(h);
    __hip_bfloat16 l = __float2bfloat16(x - fh);
    return ((uint32_t)__builtin_bit_cast(unsigned short, h) << 16)
         | (uint32_t)__builtin_bit_cast(unsigned short, l);
}

__device__ __forceinline__ float fast_tanh(float x) {
    float ax = fabsf(x);
    float e = __expf(2.0f * ax);
    float r = __builtin_amdgcn_rcpf(e + 1.0f);
    float t = fmaf(-2.0f, r, 1.0f);
    return copysignf(t, x);
}

__device__ __forceinline__ float Ffunc_f(float x, float y) {
    float e1 = __expf(-x * x - (y + 1.f) * (y + 1.f));
    float e2 = __expf(-x * x - y * y);
    float e3 = __expf(-(x + 1.f) * (x + 1.f) - y * y);
    float x3 = x * x * x;
    float y5 = y * y * y * y * y;
    return 3.f * (1.f - x) * (1.f - x) * e1
         - 10.f * (x * 0.2f - x3 - y5) * e2
         - __expf(-1.0986122886681098f * e3);
}

// Pack W1 (128x128) and W2 (128x64) into MFMA fragment order, bf16 hi/lo planes.
// Output layout in d_ws is CONTIGUOUS: w1h (2048 uint4) | w1l (2048) | w2h (1024) | w2l (1024).
__global__ void pack_weights(const float* __restrict__ W1, const float* __restrict__ W2,
                             uint4* __restrict__ w1h, uint4* __restrict__ w1l,
                             uint4* __restrict__ w2h, uint4* __restrict__ w2l)
{
    const int b = blockIdx.x;
    const int tid = threadIdx.x;
    const int s = tid >> 6, lane = tid & 63, g = lane >> 4, c = lane & 15;
    const float* W; uint4 *oh, *ol; int t, ldw;
    if (b < 8) { W = W1; oh = w1h; ol = w1l; t = b;     ldw = 128; }
    else       { W = W2; oh = w2h; ol = w2l; t = b - 8; ldw = 64;  }
    const int n = 16 * t + c;
    uint32_t hb[8], lb[8];
    #pragma unroll
    for (int j = 0; j < 8; ++j) {
        int k = 32 * s + 8 * g + j;
        float v = W[k * ldw + n];
        uint32_t h = bf_hi_bits(v);
        float fh = __uint_as_float(h << 16);
        uint32_t l = bf_hi_bits(v - fh);
        hb[j] = h; lb[j] = l;
    }
    uint4 H = make_uint4(hb[0] | (hb[1] << 16), hb[2] | (hb[3] << 16),
                         hb[4] | (hb[5] << 16), hb[6] | (hb[7] << 16));
    uint4 L = make_uint4(lb[0] | (lb[1] << 16), lb[2] | (lb[3] << 16),
                         lb[4] | (lb[5] << 16), lb[6] | (lb[7] << 16));
    oh[(t * 4 + s) * 64 + lane] = H;
    ol[(t * 4 + s) * 64 + lane] = L;
}

#define MFMA __builtin_amdgcn_mfma_f32_16x16x32_bf16

#define TPB 1024
#define NWAVE 16

// LDS offsets (in uint4 units) within the staged weight block
#define OFF_W1H 0
#define OFF_W1L 2048
#define OFF_W2H 4096
#define OFF_W2L 5120

__global__ __launch_bounds__(TPB, 4)
void fused_mlp(const int* __restrict__ data, const float* __restrict__ embed,
               const float* __restrict__ b1, const float* __restrict__ b2,
               const float* __restrict__ W3, const float* __restrict__ b3,
               const uint4* __restrict__ wpack,
               float* __restrict__ wsF, float2* __restrict__ wsO,
               int* __restrict__ wsI, int N)
{
    __shared__ __align__(16) uint4 wlds[6144];   // 96 KB staged weight fragments
    __shared__ uint32_t embs_pk[48];
    __shared__ float b1s[128], W3s[128], b2s[64], b3s[2];
    __shared__ float candF[NWAVE];
    __shared__ int candI[NWAVE];
    __shared__ float2 candO[NWAVE];

    const int tid = threadIdx.x;
    if (tid < 48) {
        float e = embed[tid];
        uint32_t h = bf_hi_bits(e);
        float fh = __uint_as_float(h << 16);
        uint32_t l = bf_hi_bits(e - fh);
        embs_pk[tid] = (h << 16) | l;
    }
    if (tid < 128) { b1s[tid] = b1[tid]; W3s[tid] = W3[tid]; }
    else if (tid < 192) b2s[tid - 128] = b2[tid - 128];
    if (tid < 2) b3s[tid] = b3[tid];

    // stage the 96 KB weight-fragment block (contiguous in global)
    #pragma unroll
    for (int u = 0; u < 6; ++u)
        wlds[u * TPB + tid] = wpack[u * TPB + tid];

    __syncthreads();

    const int w = tid >> 6, lane = tid & 63, g = lane >> 4, c = lane & 15;
    const int base = blockIdx.x << 9;              // 512 rows per block

    // ---- x fragments (hi/lo) straight from data-gather, in registers ----
    const int rowA = base + 16 * w + c;
    const size_t drow = (size_t)min(rowA, N - 1) * 128;
    uint4 xh[4], xl[4];
    #pragma unroll
    for (int s = 0; s < 4; ++s) {
        const int4* dp = (const int4*)&data[drow + 32 * s + 8 * g];
        int4 d0 = dp[0], d1 = dp[1];
        uint32_t p0 = embs_pk[d0.x], p1 = embs_pk[d0.y], p2 = embs_pk[d0.z], p3 = embs_pk[d0.w];
        uint32_t p4 = embs_pk[d1.x], p5 = embs_pk[d1.y], p6 = embs_pk[d1.z], p7 = embs_pk[d1.w];
        xh[s] = make_uint4((p1 & 0xFFFF0000u) | (p0 >> 16), (p3 & 0xFFFF0000u) | (p2 >> 16),
                           (p5 & 0xFFFF0000u) | (p4 >> 16), (p7 & 0xFFFF0000u) | (p6 >> 16));
        xl[s] = make_uint4((p1 << 16) | (p0 & 0xFFFFu), (p3 << 16) | (p2 & 0xFFFFu),
                           (p5 << 16) | (p4 & 0xFFFFu), (p7 << 16) | (p6 & 0xFFFFu));
    }

    // shuffle source lanes for the h1 quad redistribution (constant per lane)
    const int src0 = ((g & 1) << 5) + c;   // lane 32*(g&1) + c
    const int src1 = src0 + 16;

    f32x4 acc2[4];
    #pragma unroll
    for (int t2 = 0; t2 < 4; ++t2) {
        float bv = b2s[16 * t2 + c];
        acc2[t2] = (f32x4){bv, bv, bv, bv};
    }

    // ---- fused layer1 (swapped operands -> h1^T in regs) -> shuffle -> layer2 ----
    #pragma unroll
    for (int s2 = 0; s2 < 4; ++s2) {
        f32x4 aA, aB;
        #pragma unroll
        for (int r = 0; r < 4; ++r) {
            aA[r] = b1s[32 * s2 + 4 * g + r];
            aB[r] = b1s[32 * s2 + 16 + 4 * g + r];
        }
        #pragma unroll
        for (int s = 0; s < 4; ++s) {
            U4 bh0, bl0, bh1, bl1, ah, al;
            bh0.u = wlds[OFF_W1H + (8 * s2 + s) * 64 + lane];
            bl0.u = wlds[OFF_W1L + (8 * s2 + s) * 64 + lane];
            bh1.u = wlds[OFF_W1H + (8 * s2 + 4 + s) * 64 + lane];
            bl1.u = wlds[OFF_W1L + (8 * s2 + 4 + s) * 64 + lane];
            ah.u = xh[s]; al.u = xl[s];
            aA = MFMA(bh0.s, ah.s, aA, 0, 0, 0);
            aA = MFMA(bh0.s, al.s, aA, 0, 0, 0);
            aA = MFMA(bl0.s, ah.s, aA, 0, 0, 0);
            aB = MFMA(bh1.s, ah.s, aB, 0, 0, 0);
            aB = MFMA(bh1.s, al.s, aB, 0, 0, 0);
            aB = MFMA(bl1.s, ah.s, aB, 0, 0, 0);
        }
        // relu + split + pack (u32 = hi|lo), still transposed
        uint32_t pA[4], pB[4];
        #pragma unroll
        for (int r = 0; r < 4; ++r) {
            pA[r] = pack_split(fmaxf(aA[r], 0.f));
            pB[r] = pack_split(fmaxf(aB[r], 0.f));
        }
        // quad redistribution across g at fixed c
        uint32_t q0[4], q1[4];
        #pragma unroll
        for (int r = 0; r < 4; ++r) {
            uint32_t a0v = __shfl(pA[r], src0, 64);
            uint32_t b0v = __shfl(pB[r], src0, 64);
            uint32_t a1v = __shfl(pA[r], src1, 64);
            uint32_t b1v = __shfl(pB[r], src1, 64);
            q0[r] = (lane < 32) ? a0v : b0v;
            q1[r] = (lane < 32) ? a1v : b1v;
        }
        U4 ah2, al2;
        ah2.u = make_uint4((q0[1] & 0xFFFF0000u) | (q0[0] >> 16),
                           (q0[3] & 0xFFFF0000u) | (q0[2] >> 16),
                           (q1[1] & 0xFFFF0000u) | (q1[0] >> 16),
                           (q1[3] & 0xFFFF0000u) | (q1[2] >> 16));
        al2.u = make_uint4((q0[1] << 16) | (q0[0] & 0xFFFFu),
                           (q0[3] << 16) | (q0[2] & 0xFFFFu),
                           (q1[1] << 16) | (q1[0] & 0xFFFFu),
                           (q1[3] << 16) | (q1[2] & 0xFFFFu));
        // layer-2 k-slice s2
        #pragma unroll
        for (int t2 = 0; t2 < 4; ++t2) {
            U4 b2h, b2l;
            b2h.u = wlds[OFF_W2H + (t2 * 4 + s2) * 64 + lane];
            b2l.u = wlds[OFF_W2L + (t2 * 4 + s2) * 64 + lane];
            acc2[t2] = MFMA(ah2.s, b2h.s, acc2[t2], 0, 0, 0);
            acc2[t2] = MFMA(al2.s, b2h.s, acc2[t2], 0, 0, 0);
            acc2[t2] = MFMA(ah2.s, b2l.s, acc2[t2], 0, 0, 0);
        }
    }

    // ---- tanh + layer-3 partials in-register ----
    float po0[4] = {0.f, 0.f, 0.f, 0.f};
    float po1[4] = {0.f, 0.f, 0.f, 0.f};
    #pragma unroll
    for (int t2 = 0; t2 < 4; ++t2) {
        int col = 16 * t2 + c;
        float w30 = W3s[2 * col], w31 = W3s[2 * col + 1];
        #pragma unroll
        for (int r = 0; r < 4; ++r) {
            float h = fast_tanh(acc2[t2][r]);
            po0[r] = fmaf(h, w30, po0[r]);
            po1[r] = fmaf(h, w31, po1[r]);
        }
    }
    #pragma unroll
    for (int r = 0; r < 4; ++r) {
        po0[r] += __shfl_xor(po0[r], 4, 64);
        po0[r] += __shfl_xor(po0[r], 8, 64);
        po1[r] += __shfl_xor(po1[r], 4, 64);
        po1[r] += __shfl_xor(po1[r], 8, 64);
    }
    const int rsel = c >> 2;
    float v0 = (rsel == 0) ? po0[0] : (rsel == 1) ? po0[1] : (rsel == 2) ? po0[2] : po0[3];
    float v1 = (rsel == 0) ? po1[0] : (rsel == 1) ? po1[1] : (rsel == 2) ? po1[2] : po1[3];
    v0 += __shfl_xor(v0, 1, 64); v0 += __shfl_xor(v0, 2, 64);
    v1 += __shfl_xor(v1, 1, 64); v1 += __shfl_xor(v1, 2, 64);

    const int row = base + 16 * w + 4 * g + rsel;
    float o0 = v0 + b3s[0], o1 = v1 + b3s[1];
    float Fv = -INFINITY; int idx = INT_MAX;
    if (row < N) { Fv = Ffunc_f(o0, o1); idx = row; }

    #pragma unroll
    for (int m = 32; m > 0; m >>= 1) {
        float Fo = __shfl_xor(Fv, m, 64);
        int io   = __shfl_xor(idx, m, 64);
        float c0 = __shfl_xor(o0, m, 64);
        float c1 = __shfl_xor(o1, m, 64);
        if (Fo > Fv || (Fo == Fv && io < idx)) { Fv = Fo; idx = io; o0 = c0; o1 = c1; }
    }
    if (lane == 0) { candF[w] = Fv; candI[w] = idx; candO[w] = make_float2(o0, o1); }
    __syncthreads();
    if (tid == 0) {
        float bF = candF[0]; int bI = candI[0]; float2 bO = candO[0];
        #pragma unroll
        for (int u = 1; u < NWAVE; ++u) {
            if (candF[u] > bF || (candF[u] == bF && candI[u] < bI)) {
                bF = candF[u]; bI = candI[u]; bO = candO[u];
            }
        }
        wsF[blockIdx.x] = bF; wsI[blockIdx.x] = bI; wsO[blockIdx.x] = bO;
    }
}

__global__ __launch_bounds__(256, 1)
void reduce_cands(const float* __restrict__ wsF, const float2* __restrict__ wsO,
                  const int* __restrict__ wsI, int nB, float* __restrict__ out)
{
    __shared__ float sF[4];
    __shared__ int sI[4];
    __shared__ float2 sO[4];
    const int tid = threadIdx.x;
    const int w = tid >> 6, lane = tid & 63;
    float Fv = -INFINITY; int idx = INT_MAX; float2 o = make_float2(0.f, 0.f);
    for (int u = tid; u < nB; u += 256) {
        float f = wsF[u]; int i = wsI[u];
        if (f > Fv || (f == Fv && i < idx)) { Fv = f; idx = i; o = wsO[u]; }
    }
    #pragma unroll
    for (int m = 32; m > 0; m >>= 1) {
        float Fo = __shfl_xor(Fv, m, 64);
        int io   = __shfl_xor(idx, m, 64);
        float c0 = __shfl_xor(o.x, m, 64);
        float c1 = __shfl_xor(o.y, m, 64);
        if (Fo > Fv || (Fo == Fv && io < idx)) { Fv = Fo; idx = io; o = make_float2(c0, c1); }
    }
    if (lane == 0) { sF[w] = Fv; sI[w] = idx; sO[w] = o; }
    __syncthreads();
    if (tid == 0) {
        float bF = sF[0]; int bI = sI[0]; float2 bO = sO[0];
        #pragma unroll
        for (int u = 1; u < 4; ++u) {
            if (sF[u] > bF || (sF[u] == bF && sI[u] < bI)) { bF = sF[u]; bI = sI[u]; bO = sO[u]; }
        }
        out[0] = bO.x;
        out[1] = bO.y;
    }
}

extern "C" void kernel_launch(void* const* d_in, const int* in_sizes, int n_in,
                              void* d_out, int out_size, void* d_ws, size_t ws_size,
                              hipStream_t stream) {
    const int*   data  = (const int*)d_in[0];
    const float* embed = (const float*)d_in[1];
    const float* W1    = (const float*)d_in[2];
    const float* b1    = (const float*)d_in[3];
    const float* W2    = (const float*)d_in[4];
    const float* b2    = (const float*)d_in[5];
    const float* W3    = (const float*)d_in[6];
    const float* b3    = (const float*)d_in[7];

    const int N = in_sizes[0] / 128;
    const int nTiles = (N + 511) >> 9;             // 512 rows per block

    char* ws = (char*)d_ws;
    uint4* w1h = (uint4*)ws;            // 32 KB (2048 uint4)  -- contiguous 96 KB block
    uint4* w1l = w1h + 2048;            // 32 KB
    uint4* w2h = w1l + 2048;            // 16 KB (1024 uint4)
    uint4* w2l = w2h + 1024;            // 16 KB
    char* ws2 = ws + 98304;
    float2* wsO = (float2*)ws2;
    float*  wsF = (float*)(ws2 + (size_t)nTiles * 8);
    int*    wsI = (int*)(ws2 + (size_t)nTiles * 12);

    pack_weights<<<12, 256, 0, stream>>>(W1, W2, w1h, w1l, w2h, w2l);
    fused_mlp<<<nTiles, TPB, 0, stream>>>(data, embed, b1, b2, W3, b3,
                                          (const uint4*)ws, wsF, wsO, wsI, N);
    reduce_cands<<<1, 256, 0, stream>>>(wsF, wsO, wsI, nTiles, (float*)d_out);
}